// Round 12
// baseline (765.645 us; speedup 1.0000x reference)
//
#include <hip/hip_runtime.h>
#include <stdint.h>

#define M_TOT  9216   // 16*576
#define D_     768
#define CIN_   1024
#define KCODE  8192
#define TOPK   10

typedef unsigned short u16;
typedef __bf16 bf16x8 __attribute__((ext_vector_type(8)));
typedef float f32x4 __attribute__((ext_vector_type(4)));

// ---------------- helpers ----------------

__device__ inline float block_sum(float v, float* red) {
    int t = threadIdx.x;
    red[t] = v;
    __syncthreads();
    #pragma unroll
    for (int s = 128; s > 0; s >>= 1) {
        if (t < s) red[t] += red[t + s];
        __syncthreads();
    }
    float r = red[0];
    __syncthreads();
    return r;
}

__device__ inline unsigned long long umin64(unsigned long long a, unsigned long long b) {
    return (a < b) ? a : b;
}

__device__ inline u16 f2bf(float f) {          // RNE f32 -> bf16
    uint32_t u = __float_as_uint(f);
    uint32_t r = (u + 0x7fffu + ((u >> 16) & 1u)) >> 16;
    return (u16)r;
}
__device__ inline float bf2f(u16 h) {
    return __uint_as_float(((uint32_t)h) << 16);
}

__device__ inline unsigned long long shfl_xor_u64(unsigned long long v, int mask) {
    int lo = (int)(uint32_t)v, hi = (int)(uint32_t)(v >> 32);
    lo = __shfl_xor(lo, mask, 64);
    hi = __shfl_xor(hi, mask, 64);
    return ((unsigned long long)(uint32_t)hi << 32) | (uint32_t)lo;
}

#define GLDS(gp, lp) __builtin_amdgcn_global_load_lds( \
    (const __attribute__((address_space(1))) unsigned int*)(gp), \
    (__attribute__((address_space(3))) unsigned int*)(lp), 16, 0, 0)

// ---------------- GEMM1: 3-way-split bf16 MFMA, 6 terms, BK=32 swizzled -------
__global__ __launch_bounds__(256) void k_gemm1_mfma(
    const u16* __restrict__ Ah, const u16* __restrict__ Am, const u16* __restrict__ Al,
    const u16* __restrict__ Bh, const u16* __restrict__ Bm, const u16* __restrict__ Bl,
    const float* __restrict__ bias, float* __restrict__ C)
{
    __shared__ __align__(16) u16 sm[24576];   // 48KB: Ah|Am|Al|Bh|Bm|Bl, 4096 u16 each
    const int t = threadIdx.x;
    const int lane = t & 63, wid = t >> 6;
    const int row0 = blockIdx.y * 128, col0 = blockIdx.x * 128;
    const int r16 = lane & 15, kb = lane >> 4;
    const int wr = wid >> 1, wc = wid & 1;
    const int sc = (((lane & 3) ^ ((lane >> 3) & 3))) * 8;
    const int lrow = lane >> 2;
    const int swz = (r16 >> 1) & 3;

    f32x4 acc[4][4];
    #pragma unroll
    for (int mf = 0; mf < 4; ++mf)
        #pragma unroll
        for (int nf = 0; nf < 4; ++nf)
            acc[mf][nf] = (f32x4){0.f, 0.f, 0.f, 0.f};

    for (int k0 = 0; k0 < CIN_; k0 += 32) {
        __syncthreads();
        #pragma unroll
        for (int i = 0; i < 12; ++i) {
            int mat = i >> 1;
            int c = (i & 1) ? wid + 4 : wid;
            const u16* mp = (mat == 0) ? Ah : (mat == 1) ? Am : (mat == 2) ? Al
                          : (mat == 3) ? Bh : (mat == 4) ? Bm : Bl;
            int rbase = (mat < 3) ? row0 : col0;
            const u16* g = mp + (size_t)(rbase + c * 16 + lrow) * CIN_ + k0 + sc;
            GLDS(g, sm + mat * 4096 + c * 512);
        }
        __syncthreads();

        const int slot = (kb ^ swz) * 8;
        bf16x8 bh[4], bm[4], bl[4];
        #pragma unroll
        for (int nf = 0; nf < 4; ++nf) {
            int offb = 12288 + (wc * 64 + nf * 16 + r16) * 32 + slot;
            bh[nf] = *(const bf16x8*)(sm + offb);
            bm[nf] = *(const bf16x8*)(sm + offb + 4096);
            bl[nf] = *(const bf16x8*)(sm + offb + 8192);
        }
        #pragma unroll
        for (int mf = 0; mf < 4; ++mf) {
            int offa = (wr * 64 + mf * 16 + r16) * 32 + slot;
            bf16x8 ah = *(const bf16x8*)(sm + offa);
            bf16x8 am = *(const bf16x8*)(sm + offa + 4096);
            bf16x8 al = *(const bf16x8*)(sm + offa + 8192);
            #pragma unroll
            for (int nf = 0; nf < 4; ++nf) {
                acc[mf][nf] = __builtin_amdgcn_mfma_f32_16x16x32_bf16(ah, bh[nf], acc[mf][nf], 0, 0, 0);
                acc[mf][nf] = __builtin_amdgcn_mfma_f32_16x16x32_bf16(ah, bm[nf], acc[mf][nf], 0, 0, 0);
                acc[mf][nf] = __builtin_amdgcn_mfma_f32_16x16x32_bf16(am, bh[nf], acc[mf][nf], 0, 0, 0);
                acc[mf][nf] = __builtin_amdgcn_mfma_f32_16x16x32_bf16(am, bm[nf], acc[mf][nf], 0, 0, 0);
                acc[mf][nf] = __builtin_amdgcn_mfma_f32_16x16x32_bf16(ah, bl[nf], acc[mf][nf], 0, 0, 0);
                acc[mf][nf] = __builtin_amdgcn_mfma_f32_16x16x32_bf16(al, bh[nf], acc[mf][nf], 0, 0, 0);
            }
        }
    }

    #pragma unroll
    for (int mf = 0; mf < 4; ++mf) {
        #pragma unroll
        for (int q = 0; q < 4; ++q) {
            int m = row0 + wr * 64 + mf * 16 + kb * 4 + q;
            #pragma unroll
            for (int nf = 0; nf < 4; ++nf) {
                int n = col0 + wc * 64 + nf * 16 + r16;
                C[(size_t)m * D_ + n] = acc[mf][nf][q] + bias[n];
            }
        }
    }
}

// ---------------- GEMM3: 2-way-split MFMA, BK=32 swizzled dbuf, A via amin ----
__global__ __launch_bounds__(256) void k_gemm3_mfma(
    const u16* __restrict__ Eh, const u16* __restrict__ El,
    const u16* __restrict__ Ph, const u16* __restrict__ Pl,
    const unsigned long long* __restrict__ amin,
    const float* __restrict__ bias, float* __restrict__ C)
{
    __shared__ __align__(16) u16 sm[2][16384];   // 2 x 32KB: Ah|Al|Bh|Bl
    const int t = threadIdx.x;
    const int lane = t & 63, wid = t >> 6;
    const int row0 = blockIdx.y * 128, col0 = blockIdx.x * 128;
    const int r16 = lane & 15, kb = lane >> 4;
    const int wr = wid >> 1, wc = wid & 1;
    const int sc = (((lane & 3) ^ ((lane >> 3) & 3))) * 8;
    const int lrow = lane >> 2;
    const int swz = (r16 >> 1) & 3;

    const u16* sb = (wid == 0) ? Eh : (wid == 1) ? El : (wid == 2) ? Ph : Pl;
    int grow[8];
    #pragma unroll
    for (int c = 0; c < 8; ++c) {
        int r = ((wid < 2) ? row0 : col0) + c * 16 + lrow;
        grow[c] = (wid < 2) ? (int)(amin[r] & 0xFFFFFFFFull) : r;
    }

    f32x4 acc[4][4];
    #pragma unroll
    for (int mf = 0; mf < 4; ++mf)
        #pragma unroll
        for (int nf = 0; nf < 4; ++nf)
            acc[mf][nf] = (f32x4){0.f, 0.f, 0.f, 0.f};

    auto STAGE = [&](int buf, int k0) {
        u16* dst = sm[buf] + wid * 4096 + lane * 8;
        #pragma unroll
        for (int c = 0; c < 8; ++c)
            GLDS(sb + (size_t)grow[c] * D_ + k0 + sc, dst + c * 512);
    };

    STAGE(0, 0);
    __syncthreads();
    for (int kt = 0; kt < 24; ++kt) {
        int cur = kt & 1;
        if (kt < 23) STAGE(cur ^ 1, (kt + 1) * 32);
        const u16* B = sm[cur];
        const int slot = (kb ^ swz) * 8;
        bf16x8 bh[4], bl[4];
        #pragma unroll
        for (int nf = 0; nf < 4; ++nf) {
            int off = 8192 + (wc * 64 + nf * 16 + r16) * 32 + slot;
            bh[nf] = *(const bf16x8*)(B + off);
            bl[nf] = *(const bf16x8*)(B + off + 4096);
        }
        #pragma unroll
        for (int mf = 0; mf < 4; ++mf) {
            int off = (wr * 64 + mf * 16 + r16) * 32 + slot;
            bf16x8 ah = *(const bf16x8*)(B + off);
            bf16x8 al = *(const bf16x8*)(B + off + 4096);
            #pragma unroll
            for (int nf = 0; nf < 4; ++nf) {
                acc[mf][nf] = __builtin_amdgcn_mfma_f32_16x16x32_bf16(ah, bh[nf], acc[mf][nf], 0, 0, 0);
                acc[mf][nf] = __builtin_amdgcn_mfma_f32_16x16x32_bf16(ah, bl[nf], acc[mf][nf], 0, 0, 0);
                acc[mf][nf] = __builtin_amdgcn_mfma_f32_16x16x32_bf16(al, bh[nf], acc[mf][nf], 0, 0, 0);
            }
        }
        __syncthreads();
    }

    #pragma unroll
    for (int mf = 0; mf < 4; ++mf) {
        #pragma unroll
        for (int q = 0; q < 4; ++q) {
            int m = row0 + wr * 64 + mf * 16 + kb * 4 + q;
            #pragma unroll
            for (int nf = 0; nf < 4; ++nf) {
                int n = col0 + wc * 64 + nf * 16 + r16;
                C[(size_t)m * D_ + n] = acc[mf][nf][q] + bias[n];
            }
        }
    }
}

// ---------------- GEMM2: 256x256 tile, 8 waves, K=2304 virtual, counted vmcnt -
// 3-term split as a plain bf16 GEMM: A'=[Xh|Xh|Xl], B'=[Eh|El|Eh] along K.
// BK=64, 2x64KB LDS dbuf; raw s_barrier + inline vmcnt(8) (never 0 in loop):
// older tile's 8 loads complete in-order (m135), barrier gives all-wave
// visibility; re-stage only after post-compute barrier. Row%8 XOR swizzle
// (verified conflict-free) on both staging source and reads.
__global__ __launch_bounds__(512) void k_gemm2_8w(
    const u16* __restrict__ Xh, const u16* __restrict__ Xl,
    const u16* __restrict__ Eh, const u16* __restrict__ El,
    const float* __restrict__ xsq, const float* __restrict__ esq,
    const int* __restrict__ rowflag, float* __restrict__ d2row,
    unsigned long long* __restrict__ amin)
{
    __shared__ __align__(16) u16 sm[65536];   // 128KB: 2 x (A 32KB | B 32KB)
    const int tid = threadIdx.x;
    const int lane = tid & 63, wid = tid >> 6;
    const int row0 = blockIdx.y * 256, col0 = blockIdx.x * 256;
    const int r16 = lane & 15, kb = lane >> 4;
    const int wr = wid >> 2, wc = wid & 3;     // 2 x 4 wave grid; wave out: 128x64

    f32x4 acc[8][4];
    #pragma unroll
    for (int mf = 0; mf < 8; ++mf)
        #pragma unroll
        for (int nf = 0; nf < 4; ++nf)
            acc[mf][nf] = (f32x4){0.f, 0.f, 0.f, 0.f};

    auto STAGE = [&](int buf, int kt) {
        const u16* Am = (kt < 24) ? Xh : Xl;
        const u16* Bm = (kt >= 12 && kt < 24) ? El : Eh;
        const int kcol = (kt % 12) * 64;
        u16* base = sm + buf * 32768;
        #pragma unroll
        for (int c = 0; c < 4; ++c) {
            int i = c * 512 + tid;
            int rr = i >> 3;
            int kc = (i & 7) ^ (rr & 7);
            GLDS(Am + (size_t)(row0 + rr) * D_ + kcol + kc * 8, base + i * 8);
        }
        #pragma unroll
        for (int c = 0; c < 4; ++c) {
            int i = c * 512 + tid;
            int rr = i >> 3;
            int kc = (i & 7) ^ (rr & 7);
            GLDS(Bm + (size_t)(col0 + rr) * D_ + kcol + kc * 8, base + 16384 + i * 8);
        }
    };

    STAGE(0, 0);
    STAGE(1, 1);
    for (int kt = 0; kt < 36; ++kt) {
        const int cur = kt & 1;
        if (kt < 35) asm volatile("s_waitcnt vmcnt(8)" ::: "memory");
        else         asm volatile("s_waitcnt vmcnt(0)" ::: "memory");
        __builtin_amdgcn_s_barrier();
        const u16* Bb = sm + cur * 32768;
        #pragma unroll
        for (int h = 0; h < 2; ++h) {
            bf16x8 bf[4];
            #pragma unroll
            for (int nf = 0; nf < 4; ++nf) {
                int br = wc * 64 + nf * 16 + r16;
                bf[nf] = *(const bf16x8*)(Bb + 16384 + br * 64
                                          + (((h * 4 + kb) ^ (br & 7)) * 8));
            }
            #pragma unroll
            for (int mf = 0; mf < 8; ++mf) {
                int ar = wr * 128 + mf * 16 + r16;
                bf16x8 af = *(const bf16x8*)(Bb + ar * 64
                                             + (((h * 4 + kb) ^ (ar & 7)) * 8));
                #pragma unroll
                for (int nf = 0; nf < 4; ++nf)
                    acc[mf][nf] = __builtin_amdgcn_mfma_f32_16x16x32_bf16(
                        af, bf[nf], acc[mf][nf], 0, 0, 0);
            }
        }
        __builtin_amdgcn_s_barrier();
        if (kt + 2 < 36) STAGE(cur, kt + 2);
    }

    float esqv[4];
    #pragma unroll
    for (int nf = 0; nf < 4; ++nf)
        esqv[nf] = esq[col0 + wc * 64 + nf * 16 + r16];

    #pragma unroll
    for (int mf = 0; mf < 8; ++mf) {
        #pragma unroll
        for (int q = 0; q < 4; ++q) {
            int m = row0 + wr * 128 + mf * 16 + kb * 4 + q;
            float xsv = xsq[m];
            int rf = rowflag[m];
            unsigned long long best = ~0ull;
            #pragma unroll
            for (int nf = 0; nf < 4; ++nf) {
                int n = col0 + wc * 64 + nf * 16 + r16;
                float d2 = (xsv - 2.0f * acc[mf][nf][q]) + esqv[nf];
                if (rf) d2row[(size_t)(rf - 1) * KCODE + n] = d2;
                unsigned long long key =
                    ((unsigned long long)__float_as_uint(d2) << 32) | (unsigned)n;
                best = umin64(best, key);
            }
            #pragma unroll
            for (int msk = 1; msk < 16; msk <<= 1)
                best = umin64(best, shfl_xor_u64(best, msk));
            if (r16 == 0) atomicMin(&amin[m], best);
        }
    }
}

// ---------------- merged prep (all input-only work, sectioned grid) -----------
// [0,9216): img split3 | [9216,9984): lin_w split3 | [9984,10560): pos_w split2
// [10560,11136): pos encoding | [11136,11172): rowflag.  All exact-size.
__global__ __launch_bounds__(256) void k_prep(
    const float* __restrict__ img, u16* __restrict__ Ih, u16* __restrict__ Im,
    u16* __restrict__ Il,
    const float* __restrict__ lin_w, u16* __restrict__ Wh, u16* __restrict__ Wm,
    u16* __restrict__ Wl,
    const float* __restrict__ pos_w, u16* __restrict__ Ph, u16* __restrict__ Pl,
    float* __restrict__ pos,
    const int* __restrict__ mask, int* __restrict__ rowflag)
{
    int bid = blockIdx.x, t = threadIdx.x;
    if (bid < 9216) {
        int i = bid * 256 + t;
        float4 v = ((const float4*)img)[i];
        ushort4 hv, mv, lv;
        float x, r;
        x = v.x; hv.x = f2bf(x); r = x - bf2f(hv.x); mv.x = f2bf(r); lv.x = f2bf(r - bf2f(mv.x));
        x = v.y; hv.y = f2bf(x); r = x - bf2f(hv.y); mv.y = f2bf(r); lv.y = f2bf(r - bf2f(mv.y));
        x = v.z; hv.z = f2bf(x); r = x - bf2f(hv.z); mv.z = f2bf(r); lv.z = f2bf(r - bf2f(mv.z));
        x = v.w; hv.w = f2bf(x); r = x - bf2f(hv.w); mv.w = f2bf(r); lv.w = f2bf(r - bf2f(mv.w));
        ((ushort4*)Ih)[i] = hv; ((ushort4*)Im)[i] = mv; ((ushort4*)Il)[i] = lv;
    } else if (bid < 9984) {
        int i = (bid - 9216) * 256 + t;
        float4 v = ((const float4*)lin_w)[i];
        ushort4 hv, mv, lv;
        float x, r;
        x = v.x; hv.x = f2bf(x); r = x - bf2f(hv.x); mv.x = f2bf(r); lv.x = f2bf(r - bf2f(mv.x));
        x = v.y; hv.y = f2bf(x); r = x - bf2f(hv.y); mv.y = f2bf(r); lv.y = f2bf(r - bf2f(mv.y));
        x = v.z; hv.z = f2bf(x); r = x - bf2f(hv.z); mv.z = f2bf(r); lv.z = f2bf(r - bf2f(mv.z));
        x = v.w; hv.w = f2bf(x); r = x - bf2f(hv.w); mv.w = f2bf(r); lv.w = f2bf(r - bf2f(mv.w));
        ((ushort4*)Wh)[i] = hv; ((ushort4*)Wm)[i] = mv; ((ushort4*)Wl)[i] = lv;
    } else if (bid < 10560) {
        int i = (bid - 9984) * 256 + t;
        float4 v = ((const float4*)pos_w)[i];
        ushort4 hv, lv;
        hv.x = f2bf(v.x); lv.x = f2bf(v.x - bf2f(hv.x));
        hv.y = f2bf(v.y); lv.y = f2bf(v.y - bf2f(hv.y));
        hv.z = f2bf(v.z); lv.z = f2bf(v.z - bf2f(hv.z));
        hv.w = f2bf(v.w); lv.w = f2bf(v.w - bf2f(hv.w));
        ((ushort4*)Ph)[i] = hv; ((ushort4*)Pl)[i] = lv;
    } else if (bid < 11136) {
        int l = bid - 10560;
        for (int k = t; k < D_; k += 256) {
            int kk = (k < 384) ? k : k - 384;
            int m = kk >> 1;
            float coord = (k < 384) ? (float)(l / 24) : (float)(l % 24);
            float v = (coord + 1.0f) / 24.000001f * 6.28318530717958647692f;
            float tm = exp2f((float)m * (13.287712379549449f / 192.0f));
            float a = v / tm;
            pos[(size_t)l * D_ + k] = (kk & 1) ? cosf(a) : sinf(a);
        }
    } else {
        int i = (bid - 11136) * 256 + t;
        int b = i / 576, l = i - b * 576;
        rowflag[i] = (mask[b] == l) ? (b + 1) : 0;
    }
}

// ---------------- merged: LN1+ReLU+xsq+X-split  |  esq+E-split ----------------
__global__ __launch_bounds__(256) void k_ln_esq(
    const float* __restrict__ in, const float* __restrict__ w,
    const float* __restrict__ b, float* __restrict__ xq, float* __restrict__ xsq,
    u16* __restrict__ Xh, u16* __restrict__ Xl,
    const float* __restrict__ E, float* __restrict__ esq,
    u16* __restrict__ Eh, u16* __restrict__ El)
{
    __shared__ float red[256];
    int t = threadIdx.x;
    if (blockIdx.x < 9216) {
        int r = blockIdx.x;
        const float* row = in + (size_t)r * D_;
        float v0 = row[t], v1 = row[t + 256], v2 = row[t + 512];
        float mu = block_sum(v0 + v1 + v2, red) * (1.0f / 768.0f);
        float d0 = v0 - mu, d1 = v1 - mu, d2 = v2 - mu;
        float var = block_sum(d0 * d0 + d1 * d1 + d2 * d2, red) * (1.0f / 768.0f);
        float rn = 1.0f / sqrtf(var + 1e-5f);
        float o0 = fmaxf(0.0f, d0 * rn * w[t] + b[t]);
        float o1 = fmaxf(0.0f, d1 * rn * w[t + 256] + b[t + 256]);
        float o2 = fmaxf(0.0f, d2 * rn * w[t + 512] + b[t + 512]);
        float* orow = xq + (size_t)r * D_;
        orow[t] = o0; orow[t + 256] = o1; orow[t + 512] = o2;
        u16 h0 = f2bf(o0), h1 = f2bf(o1), h2 = f2bf(o2);
        Xh[(size_t)r * D_ + t]       = h0;
        Xh[(size_t)r * D_ + t + 256] = h1;
        Xh[(size_t)r * D_ + t + 512] = h2;
        Xl[(size_t)r * D_ + t]       = f2bf(o0 - bf2f(h0));
        Xl[(size_t)r * D_ + t + 256] = f2bf(o1 - bf2f(h1));
        Xl[(size_t)r * D_ + t + 512] = f2bf(o2 - bf2f(h2));
        float q = block_sum(o0 * o0 + o1 * o1 + o2 * o2, red);
        if (t == 0) xsq[r] = q;
    } else {
        int r = blockIdx.x - 9216;
        const float* row = E + (size_t)r * D_;
        float v0 = row[t], v1 = row[t + 256], v2 = row[t + 512];
        u16 h0 = f2bf(v0), h1 = f2bf(v1), h2 = f2bf(v2);
        Eh[(size_t)r * D_ + t]       = h0;
        Eh[(size_t)r * D_ + t + 256] = h1;
        Eh[(size_t)r * D_ + t + 512] = h2;
        El[(size_t)r * D_ + t]       = f2bf(v0 - bf2f(h0));
        El[(size_t)r * D_ + t + 256] = f2bf(v1 - bf2f(h1));
        El[(size_t)r * D_ + t + 512] = f2bf(v2 - bf2f(h2));
        float s = block_sum(v0 * v0 + v1 * v1 + v2 * v2, red);
        if (t == 0) esq[r] = s;
    }
}

// ---------------- threefry2x32 (jax key(42)) ----------------
__device__ inline void threefry2x32(uint32_t x0, uint32_t x1,
                                    uint32_t& o0, uint32_t& o1)
{
    const uint32_t ks0 = 0u, ks1 = 42u;
    const uint32_t ks2 = ks0 ^ ks1 ^ 0x1BD11BDAu;
    uint32_t ks[3] = {ks0, ks1, ks2};
    x0 += ks[0]; x1 += ks[1];
    const int R0[4] = {13, 15, 26, 6};
    const int R1[4] = {17, 29, 16, 24};
    #pragma unroll
    for (int i = 0; i < 5; ++i) {
        const int* R = (i & 1) ? R1 : R0;
        #pragma unroll
        for (int q = 0; q < 4; ++q) {
            x0 += x1;
            x1 = (x1 << R[q]) | (x1 >> (32 - R[q]));
            x1 ^= x0;
        }
        x0 += ks[(i + 1) % 3];
        x1 += ks[(i + 2) % 3] + (uint32_t)(i + 1);
    }
    o0 = x0; o1 = x1;
}

// ---------------- top-10 + softmax + gumbel categorical, 16 rows ----------------
__global__ __launch_bounds__(256) void k_topk_sample(
    const float* __restrict__ d2row, const unsigned long long* __restrict__ amin,
    const int* __restrict__ mask, int* __restrict__ mlabel, int* __restrict__ negsel)
{
    __shared__ float sd2[KCODE];
    __shared__ unsigned long long rbuf[256];
    __shared__ float rfs[256];
    __shared__ int sel[TOPK];
    __shared__ float selv[TOPK];
    __shared__ float sS;
    int b = blockIdx.x, t = threadIdx.x;
    for (int j = t; j < KCODE; j += 256) sd2[j] = d2row[b * KCODE + j];
    __syncthreads();
    for (int p = 0; p < TOPK; ++p) {
        unsigned long long best = ~0ull;
        for (int j = t; j < KCODE; j += 256) {
            bool skip = false;
            for (int q = 0; q < p; ++q) skip = skip || (j == sel[q]);
            if (skip) continue;
            unsigned long long key =
                ((unsigned long long)__float_as_uint(sd2[j]) << 32) | (unsigned)j;
            best = umin64(best, key);
        }
        rbuf[t] = best;
        __syncthreads();
        for (int s = 128; s > 0; s >>= 1) {
            if (t < s) rbuf[t] = umin64(rbuf[t], rbuf[t + s]);
            __syncthreads();
        }
        if (t == 0) {
            sel[p] = (int)(rbuf[0] & 0xFFFFFFFFull);
            selv[p] = __uint_as_float((uint32_t)(rbuf[0] >> 32));
        }
        __syncthreads();
    }
    float d2min = selv[0];
    float part = 0.0f;
    for (int j = t; j < KCODE; j += 256) part += expf(d2min - sd2[j]);
    part = block_sum(part, rfs);
    if (t == 0) sS = part;
    __syncthreads();
    if (t == 0) {
        int rb = b * 576 + mask[b];
        mlabel[b] = (int)(amin[rb] & 0xFFFFFFFFull);
        float S = sS;
        float bestv = 0.0f;
        int samp = 0;
        bool first = true;
        for (int k = 0; k < TOPK; ++k) {
            float pk = expf(d2min - selv[k]) / S;
            float logit = logf(pk);
            unsigned f = (unsigned)(rb * 10 + k);
            uint32_t o0, o1;
            threefry2x32(0u, f, o0, o1);
            uint32_t bits = o0 ^ o1;
            float uu = __uint_as_float(0x3F800000u | (bits >> 9)) - 1.0f;
            uu = uu + 1.1754944e-38f;
            uu = fmaxf(1.1754944e-38f, uu);
            float gum = -logf(-logf(uu));
            float sc = logit + gum;
            if (first || sc > bestv) { bestv = sc; samp = k; first = false; }
        }
        negsel[b] = sel[samp];
    }
}

// ---------------- fused gate + final: GEMV+LN2+softmax, mix, +pos, LN x2 ------
__global__ __launch_bounds__(256) void k_gate_final(
    const float* __restrict__ embpt, const float* __restrict__ xq,
    const unsigned long long* __restrict__ amin,
    const int* __restrict__ mlabel, const int* __restrict__ negsel,
    const float* __restrict__ E, const float* __restrict__ pos,
    const float* __restrict__ gw, const float* __restrict__ gb,
    const float* __restrict__ glnw, const float* __restrict__ glnb,
    const float* __restrict__ ow, const float* __restrict__ ob,
    float* __restrict__ outp, float* __restrict__ outn)
{
    __shared__ float red[256];
    __shared__ float ss0, ss1;
    int r = blockIdx.x, t = threadIdx.x;
    int b = r / 576, l = r % 576;
    const float* ep = embpt + (size_t)r * D_;
    const float* xr = xq + (size_t)r * D_;

    // gate (identical arithmetic to the previous k_gate)
    float g0 = 0.0f, g1 = 0.0f;
    for (int k = t; k < 1536; k += 256) {
        float v = (k < 768) ? ep[k] : xr[k - 768];
        g0 = fmaf(v, gw[k], g0);
        g1 = fmaf(v, gw[1536 + k], g1);
    }
    g0 = block_sum(g0, red);
    g1 = block_sum(g1, red);
    if (t == 0) {
        g0 += gb[0]; g1 += gb[1];
        float mu = 0.5f * (g0 + g1);
        float h0 = g0 - mu, h1 = g1 - mu;
        float var = 0.5f * (h0 * h0 + h1 * h1);
        float rn = 1.0f / sqrtf(var + 1e-5f);
        float o0 = fmaxf(0.0f, h0 * rn * glnw[0] + glnb[0]);
        float o1 = fmaxf(0.0f, h1 * rn * glnw[1] + glnb[1]);
        float m = fmaxf(o0, o1);
        float e0 = expf(o0 - m), e1 = expf(o1 - m);
        float inv = 1.0f / (e0 + e1);
        ss0 = e0 * inv;
        ss1 = e1 * inv;
    }
    __syncthreads();
    float s0 = ss0, s1 = ss1;

    int ir = (int)(amin[r] & 0xFFFFFFFFull);
    int nidx = (ir == mlabel[b]) ? negsel[b] : ir;
    const float* er = E + (size_t)nidx * D_;
    const float* pr = pos + (size_t)l * D_;
    float vp[3], vn[3];
    #pragma unroll
    for (int q = 0; q < 3; ++q) {
        int k = t + q * 256;
        float xv = xr[k] * s1;
        float pv = pr[k];
        vp[q] = (ep[k] * s0 + xv) + pv;
        vn[q] = (er[k] * s0 + xv) + pv;
    }
    float mup = block_sum(vp[0] + vp[1] + vp[2], red) * (1.0f / 768.0f);
    float a0 = vp[0] - mup, a1 = vp[1] - mup, a2 = vp[2] - mup;
    float varp = block_sum(a0 * a0 + a1 * a1 + a2 * a2, red) * (1.0f / 768.0f);
    float rnp = 1.0f / sqrtf(varp + 1e-5f);
    float mun = block_sum(vn[0] + vn[1] + vn[2], red) * (1.0f / 768.0f);
    float c0 = vn[0] - mun, c1 = vn[1] - mun, c2 = vn[2] - mun;
    float varn = block_sum(c0 * c0 + c1 * c1 + c2 * c2, red) * (1.0f / 768.0f);
    float rnn = 1.0f / sqrtf(varn + 1e-5f);
    float* op = outp + (size_t)r * D_;
    float* on = outn + (size_t)r * D_;
    op[t]       = a0 * rnp * ow[t]       + ob[t];
    op[t + 256] = a1 * rnp * ow[t + 256] + ob[t + 256];
    op[t + 512] = a2 * rnp * ow[t + 512] + ob[t + 512];
    on[t]       = c0 * rnn * ow[t]       + ob[t];
    on[t + 256] = c1 * rnn * ow[t + 256] + ob[t + 256];
    on[t + 512] = c2 * rnn * ow[t + 512] + ob[t + 512];
}

// ---------------- launcher ----------------
extern "C" void kernel_launch(void* const* d_in, const int* in_sizes, int n_in,
                              void* d_out, int out_size, void* d_ws, size_t ws_size,
                              hipStream_t stream)
{
    (void)in_sizes; (void)n_in; (void)out_size; (void)ws_size;
    const float* img    = (const float*)d_in[0];
    const int*   maski  = (const int*)d_in[1];
    const float* lin_w  = (const float*)d_in[2];
    const float* lin_b  = (const float*)d_in[3];
    const float* ln1_w  = (const float*)d_in[4];
    const float* ln1_b  = (const float*)d_in[5];
    const float* embed  = (const float*)d_in[6];
    const float* pos_w  = (const float*)d_in[7];
    const float* pos_b  = (const float*)d_in[8];
    const float* gate_w = (const float*)d_in[9];
    const float* gate_b = (const float*)d_in[10];
    const float* glnw   = (const float*)d_in[11];
    const float* glnb   = (const float*)d_in[12];
    const float* olnw   = (const float*)d_in[13];
    const float* olnb   = (const float*)d_in[14];

    uint8_t* wp = (uint8_t*)d_ws;
    auto alloc = [&](size_t bytes) -> void* {
        void* p = (void*)wp;
        wp += (bytes + 255) & ~(size_t)255;
        return p;
    };
    float* bufA = (float*)alloc((size_t)M_TOT * D_ * 4);   // gemm1 out, later emb_pt
    float* xq   = (float*)alloc((size_t)M_TOT * D_ * 4);
    float* xsq  = (float*)alloc((size_t)M_TOT * 4);
    float* esq  = (float*)alloc((size_t)KCODE * 4);
    unsigned long long* amin = (unsigned long long*)alloc((size_t)M_TOT * 8);
    int*   rowflag = (int*)alloc((size_t)M_TOT * 4);
    float* posb   = (float*)alloc((size_t)576 * D_ * 4);
    float* d2row  = (float*)alloc((size_t)16 * KCODE * 4);
    int*   mlab   = (int*)alloc(16 * 4);
    int*   negsel = (int*)alloc(16 * 4);
    u16* Wh = (u16*)alloc((size_t)D_ * CIN_ * 2);
    u16* Wm = (u16*)alloc((size_t)D_ * CIN_ * 2);
    u16* Wl = (u16*)alloc((size_t)D_ * CIN_ * 2);
    u16* Ph = (u16*)alloc((size_t)D_ * D_ * 2);
    u16* Pl = (u16*)alloc((size_t)D_ * D_ * 2);
    // R region: img 3-way splits (dead after gemm1), then reused for X/E splits
    u16* R  = (u16*)alloc((size_t)3 * M_TOT * CIN_ * 2);
    u16* Ih = R;
    u16* Im = R + (size_t)M_TOT * CIN_;
    u16* Il = R + (size_t)2 * M_TOT * CIN_;
    u16* Xh = R;
    u16* Xl = Xh + (size_t)M_TOT * D_;
    u16* Eh = Xl + (size_t)M_TOT * D_;
    u16* El = Eh + (size_t)KCODE * D_;

    float* outp = (float*)d_out;
    float* outn = outp + (size_t)M_TOT * D_;

    hipMemsetAsync(amin, 0xFF, M_TOT * sizeof(unsigned long long), stream);

    dim3 blk(256);
    // 0) merged prep
    k_prep<<<11172, blk, 0, stream>>>(img, Ih, Im, Il, lin_w, Wh, Wm, Wl,
                                      pos_w, Ph, Pl, posb, maski, rowflag);
    // 1) xq_pre = img @ lin_w^T + lin_b
    k_gemm1_mfma<<<dim3(D_ / 128, M_TOT / 128), blk, 0, stream>>>(
        Ih, Im, Il, Wh, Wm, Wl, lin_b, bufA);
    // 2) merged LN+ReLU+xsq+X-split | esq+E-split
    k_ln_esq<<<17408, blk, 0, stream>>>(bufA, ln1_w, ln1_b, xq, xsq, Xh, Xl,
                                        embed, esq, Eh, El);
    // 3) code-search: 256x256 8-wave counted-vmcnt GEMM + argmin + d2 capture
    k_gemm2_8w<<<dim3(KCODE / 256, M_TOT / 256), dim3(512), 0, stream>>>(
        Xh, Xl, Eh, El, xsq, esq, rowflag, d2row, amin);
    // 4) emb_pt = embed[idx] @ pos_w^T + pos_b
    k_gemm3_mfma<<<dim3(D_ / 128, M_TOT / 128), blk, 0, stream>>>(
        Eh, El, Ph, Pl, amin, pos_b, bufA);
    // 5) top-10 + threefry gumbel categorical
    k_topk_sample<<<16, blk, 0, stream>>>(d2row, amin, maski, mlab, negsel);
    // 6) fused gate + final mix + LN x2
    k_gate_final<<<M_TOT, blk, 0, stream>>>(bufA, xq, amin, mlab, negsel,
                                            embed, posb, gate_w, gate_b,
                                            glnw, glnb, olnw, olnb, outp, outn);
}

// Round 13
// 740.288 us; speedup vs baseline: 1.0343x; 1.0343x over previous
//
#include <hip/hip_runtime.h>
#include <stdint.h>

#define M_TOT  9216   // 16*576
#define D_     768
#define CIN_   1024
#define KCODE  8192
#define TOPK   10

typedef unsigned short u16;
typedef __bf16 bf16x8 __attribute__((ext_vector_type(8)));
typedef float f32x4 __attribute__((ext_vector_type(4)));

// ---------------- helpers ----------------

__device__ inline float block_sum(float v, float* red) {
    int t = threadIdx.x;
    red[t] = v;
    __syncthreads();
    #pragma unroll
    for (int s = 128; s > 0; s >>= 1) {
        if (t < s) red[t] += red[t + s];
        __syncthreads();
    }
    float r = red[0];
    __syncthreads();
    return r;
}

__device__ inline unsigned long long umin64(unsigned long long a, unsigned long long b) {
    return (a < b) ? a : b;
}

__device__ inline u16 f2bf(float f) {          // RNE f32 -> bf16
    uint32_t u = __float_as_uint(f);
    uint32_t r = (u + 0x7fffu + ((u >> 16) & 1u)) >> 16;
    return (u16)r;
}
__device__ inline float bf2f(u16 h) {
    return __uint_as_float(((uint32_t)h) << 16);
}

__device__ inline unsigned long long shfl_xor_u64(unsigned long long v, int mask) {
    int lo = (int)(uint32_t)v, hi = (int)(uint32_t)(v >> 32);
    lo = __shfl_xor(lo, mask, 64);
    hi = __shfl_xor(hi, mask, 64);
    return ((unsigned long long)(uint32_t)hi << 32) | (uint32_t)lo;
}

#define GLDS(gp, lp) __builtin_amdgcn_global_load_lds( \
    (const __attribute__((address_space(1))) unsigned int*)(gp), \
    (__attribute__((address_space(3))) unsigned int*)(lp), 16, 0, 0)

// ---------------- GEMM1: 3-way-split bf16 MFMA, 6 terms, BK=32 swizzled -------
__global__ __launch_bounds__(256) void k_gemm1_mfma(
    const u16* __restrict__ Ah, const u16* __restrict__ Am, const u16* __restrict__ Al,
    const u16* __restrict__ Bh, const u16* __restrict__ Bm, const u16* __restrict__ Bl,
    const float* __restrict__ bias, float* __restrict__ C)
{
    __shared__ __align__(16) u16 sm[24576];   // 48KB: Ah|Am|Al|Bh|Bm|Bl, 4096 u16 each
    const int t = threadIdx.x;
    const int lane = t & 63, wid = t >> 6;
    const int row0 = blockIdx.y * 128, col0 = blockIdx.x * 128;
    const int r16 = lane & 15, kb = lane >> 4;
    const int wr = wid >> 1, wc = wid & 1;
    const int sc = (((lane & 3) ^ ((lane >> 3) & 3))) * 8;
    const int lrow = lane >> 2;
    const int swz = (r16 >> 1) & 3;

    f32x4 acc[4][4];
    #pragma unroll
    for (int mf = 0; mf < 4; ++mf)
        #pragma unroll
        for (int nf = 0; nf < 4; ++nf)
            acc[mf][nf] = (f32x4){0.f, 0.f, 0.f, 0.f};

    for (int k0 = 0; k0 < CIN_; k0 += 32) {
        __syncthreads();
        #pragma unroll
        for (int i = 0; i < 12; ++i) {
            int mat = i >> 1;
            int c = (i & 1) ? wid + 4 : wid;
            const u16* mp = (mat == 0) ? Ah : (mat == 1) ? Am : (mat == 2) ? Al
                          : (mat == 3) ? Bh : (mat == 4) ? Bm : Bl;
            int rbase = (mat < 3) ? row0 : col0;
            const u16* g = mp + (size_t)(rbase + c * 16 + lrow) * CIN_ + k0 + sc;
            GLDS(g, sm + mat * 4096 + c * 512);
        }
        __syncthreads();

        const int slot = (kb ^ swz) * 8;
        bf16x8 bh[4], bm[4], bl[4];
        #pragma unroll
        for (int nf = 0; nf < 4; ++nf) {
            int offb = 12288 + (wc * 64 + nf * 16 + r16) * 32 + slot;
            bh[nf] = *(const bf16x8*)(sm + offb);
            bm[nf] = *(const bf16x8*)(sm + offb + 4096);
            bl[nf] = *(const bf16x8*)(sm + offb + 8192);
        }
        #pragma unroll
        for (int mf = 0; mf < 4; ++mf) {
            int offa = (wr * 64 + mf * 16 + r16) * 32 + slot;
            bf16x8 ah = *(const bf16x8*)(sm + offa);
            bf16x8 am = *(const bf16x8*)(sm + offa + 4096);
            bf16x8 al = *(const bf16x8*)(sm + offa + 8192);
            #pragma unroll
            for (int nf = 0; nf < 4; ++nf) {
                acc[mf][nf] = __builtin_amdgcn_mfma_f32_16x16x32_bf16(ah, bh[nf], acc[mf][nf], 0, 0, 0);
                acc[mf][nf] = __builtin_amdgcn_mfma_f32_16x16x32_bf16(ah, bm[nf], acc[mf][nf], 0, 0, 0);
                acc[mf][nf] = __builtin_amdgcn_mfma_f32_16x16x32_bf16(am, bh[nf], acc[mf][nf], 0, 0, 0);
                acc[mf][nf] = __builtin_amdgcn_mfma_f32_16x16x32_bf16(am, bm[nf], acc[mf][nf], 0, 0, 0);
                acc[mf][nf] = __builtin_amdgcn_mfma_f32_16x16x32_bf16(ah, bl[nf], acc[mf][nf], 0, 0, 0);
                acc[mf][nf] = __builtin_amdgcn_mfma_f32_16x16x32_bf16(al, bh[nf], acc[mf][nf], 0, 0, 0);
            }
        }
    }

    #pragma unroll
    for (int mf = 0; mf < 4; ++mf) {
        #pragma unroll
        for (int q = 0; q < 4; ++q) {
            int m = row0 + wr * 64 + mf * 16 + kb * 4 + q;
            #pragma unroll
            for (int nf = 0; nf < 4; ++nf) {
                int n = col0 + wc * 64 + nf * 16 + r16;
                C[(size_t)m * D_ + n] = acc[mf][nf][q] + bias[n];
            }
        }
    }
}

// ---------------- GEMM3: 2-way-split MFMA, BK=32 swizzled dbuf, A via amin ----
__global__ __launch_bounds__(256) void k_gemm3_mfma(
    const u16* __restrict__ Eh, const u16* __restrict__ El,
    const u16* __restrict__ Ph, const u16* __restrict__ Pl,
    const unsigned long long* __restrict__ amin,
    const float* __restrict__ bias, float* __restrict__ C)
{
    __shared__ __align__(16) u16 sm[2][16384];   // 2 x 32KB: Ah|Al|Bh|Bl
    const int t = threadIdx.x;
    const int lane = t & 63, wid = t >> 6;
    const int row0 = blockIdx.y * 128, col0 = blockIdx.x * 128;
    const int r16 = lane & 15, kb = lane >> 4;
    const int wr = wid >> 1, wc = wid & 1;
    const int sc = (((lane & 3) ^ ((lane >> 3) & 3))) * 8;
    const int lrow = lane >> 2;
    const int swz = (r16 >> 1) & 3;

    const u16* sb = (wid == 0) ? Eh : (wid == 1) ? El : (wid == 2) ? Ph : Pl;
    int grow[8];
    #pragma unroll
    for (int c = 0; c < 8; ++c) {
        int r = ((wid < 2) ? row0 : col0) + c * 16 + lrow;
        grow[c] = (wid < 2) ? (int)(amin[r] & 0xFFFFFFFFull) : r;
    }

    f32x4 acc[4][4];
    #pragma unroll
    for (int mf = 0; mf < 4; ++mf)
        #pragma unroll
        for (int nf = 0; nf < 4; ++nf)
            acc[mf][nf] = (f32x4){0.f, 0.f, 0.f, 0.f};

    auto STAGE = [&](int buf, int k0) {
        u16* dst = sm[buf] + wid * 4096 + lane * 8;
        #pragma unroll
        for (int c = 0; c < 8; ++c)
            GLDS(sb + (size_t)grow[c] * D_ + k0 + sc, dst + c * 512);
    };

    STAGE(0, 0);
    __syncthreads();
    for (int kt = 0; kt < 24; ++kt) {
        int cur = kt & 1;
        if (kt < 23) STAGE(cur ^ 1, (kt + 1) * 32);
        const u16* B = sm[cur];
        const int slot = (kb ^ swz) * 8;
        bf16x8 bh[4], bl[4];
        #pragma unroll
        for (int nf = 0; nf < 4; ++nf) {
            int off = 8192 + (wc * 64 + nf * 16 + r16) * 32 + slot;
            bh[nf] = *(const bf16x8*)(B + off);
            bl[nf] = *(const bf16x8*)(B + off + 4096);
        }
        #pragma unroll
        for (int mf = 0; mf < 4; ++mf) {
            int off = (wr * 64 + mf * 16 + r16) * 32 + slot;
            bf16x8 ah = *(const bf16x8*)(B + off);
            bf16x8 al = *(const bf16x8*)(B + off + 4096);
            #pragma unroll
            for (int nf = 0; nf < 4; ++nf) {
                acc[mf][nf] = __builtin_amdgcn_mfma_f32_16x16x32_bf16(ah, bh[nf], acc[mf][nf], 0, 0, 0);
                acc[mf][nf] = __builtin_amdgcn_mfma_f32_16x16x32_bf16(ah, bl[nf], acc[mf][nf], 0, 0, 0);
                acc[mf][nf] = __builtin_amdgcn_mfma_f32_16x16x32_bf16(al, bh[nf], acc[mf][nf], 0, 0, 0);
            }
        }
        __syncthreads();
    }

    #pragma unroll
    for (int mf = 0; mf < 4; ++mf) {
        #pragma unroll
        for (int q = 0; q < 4; ++q) {
            int m = row0 + wr * 64 + mf * 16 + kb * 4 + q;
            #pragma unroll
            for (int nf = 0; nf < 4; ++nf) {
                int n = col0 + wc * 64 + nf * 16 + r16;
                C[(size_t)m * D_ + n] = acc[mf][nf][q] + bias[n];
            }
        }
    }
}

// ---------------- GEMM2: round-8/11 verified — BK=64 XOR-swizzled, sbuf -------
// ~379us, MfmaUtil ~41%, 0 conflicts, 2 blocks/CU; 915 TF effective = the
// documented ~900TF 2-barrier structural ceiling. Fused d2+argmin+masked-row d2.
__global__ __launch_bounds__(256) void k_gemm2_mfma(
    const u16* __restrict__ Xh, const u16* __restrict__ Xl,
    const u16* __restrict__ Eh, const u16* __restrict__ El,
    const float* __restrict__ xsq, const float* __restrict__ esq,
    const int* __restrict__ rowflag, float* __restrict__ d2row,
    unsigned long long* __restrict__ amin)
{
    __shared__ __align__(16) u16 sm[32768];   // 64KB: Ah|Al|Bh|Bl each 8192 u16
    const int t = threadIdx.x;
    const int lane = t & 63, wid = t >> 6;
    const int row0 = blockIdx.y * 128, col0 = blockIdx.x * 128;
    const int r16 = lane & 15, kb = lane >> 4;
    const int wr = wid >> 1, wc = wid & 1;

    f32x4 acc[4][4];
    #pragma unroll
    for (int mf = 0; mf < 4; ++mf)
        #pragma unroll
        for (int nf = 0; nf < 4; ++nf)
            acc[mf][nf] = (f32x4){0.f, 0.f, 0.f, 0.f};

    const u16* sb = (wid == 0) ? Xh : (wid == 1) ? Xl : (wid == 2) ? Eh : El;
    const int rbase = (wid < 2) ? row0 : col0;
    const u16* srcb = sb + (size_t)(rbase + (lane >> 3)) * D_
                         + ((lane & 7) ^ (lane >> 3)) * 8;
    u16* dstb = sm + wid * 8192 + lane * 8;

    const int swz = (r16 & 7);
    for (int kt = 0; kt < 12; ++kt) {
        __syncthreads();
        #pragma unroll
        for (int c = 0; c < 16; ++c) {
            GLDS(srcb + kt * 64 + c * 8 * D_, dstb + c * 512);
        }
        __syncthreads();
        #pragma unroll
        for (int h = 0; h < 2; ++h) {
            const int slot = ((h * 4 + kb) ^ swz) * 8;
            bf16x8 bh[4], bl[4];
            #pragma unroll
            for (int nf = 0; nf < 4; ++nf) {
                int off = (wc * 64 + nf * 16 + r16) * 64 + slot;
                bh[nf] = *(const bf16x8*)(sm + 16384 + off);
                bl[nf] = *(const bf16x8*)(sm + 24576 + off);
            }
            #pragma unroll
            for (int mf = 0; mf < 4; ++mf) {
                int off = (wr * 64 + mf * 16 + r16) * 64 + slot;
                bf16x8 ah = *(const bf16x8*)(sm + off);
                bf16x8 al = *(const bf16x8*)(sm + 8192 + off);
                #pragma unroll
                for (int nf = 0; nf < 4; ++nf) {
                    acc[mf][nf] = __builtin_amdgcn_mfma_f32_16x16x32_bf16(ah, bh[nf], acc[mf][nf], 0, 0, 0);
                    acc[mf][nf] = __builtin_amdgcn_mfma_f32_16x16x32_bf16(ah, bl[nf], acc[mf][nf], 0, 0, 0);
                    acc[mf][nf] = __builtin_amdgcn_mfma_f32_16x16x32_bf16(al, bh[nf], acc[mf][nf], 0, 0, 0);
                }
            }
        }
    }

    float esqv[4];
    #pragma unroll
    for (int nf = 0; nf < 4; ++nf)
        esqv[nf] = esq[col0 + wc * 64 + nf * 16 + r16];

    #pragma unroll
    for (int mf = 0; mf < 4; ++mf) {
        #pragma unroll
        for (int q = 0; q < 4; ++q) {
            int m = row0 + wr * 64 + mf * 16 + kb * 4 + q;
            float xsv = xsq[m];
            int rf = rowflag[m];
            unsigned long long best = ~0ull;
            #pragma unroll
            for (int nf = 0; nf < 4; ++nf) {
                int n = col0 + wc * 64 + nf * 16 + r16;
                float d2 = (xsv - 2.0f * acc[mf][nf][q]) + esqv[nf];
                if (rf) d2row[(size_t)(rf - 1) * KCODE + n] = d2;
                unsigned long long key =
                    ((unsigned long long)__float_as_uint(d2) << 32) | (unsigned)n;
                best = umin64(best, key);
            }
            #pragma unroll
            for (int msk = 1; msk < 16; msk <<= 1)
                best = umin64(best, shfl_xor_u64(best, msk));
            if (r16 == 0) atomicMin(&amin[m], best);
        }
    }
}

// ---------------- merged prep (all input-only work, sectioned grid) -----------
__global__ __launch_bounds__(256) void k_prep(
    const float* __restrict__ img, u16* __restrict__ Ih, u16* __restrict__ Im,
    u16* __restrict__ Il,
    const float* __restrict__ lin_w, u16* __restrict__ Wh, u16* __restrict__ Wm,
    u16* __restrict__ Wl,
    const float* __restrict__ pos_w, u16* __restrict__ Ph, u16* __restrict__ Pl,
    float* __restrict__ pos,
    const int* __restrict__ mask, int* __restrict__ rowflag)
{
    int bid = blockIdx.x, t = threadIdx.x;
    if (bid < 9216) {
        int i = bid * 256 + t;
        float4 v = ((const float4*)img)[i];
        ushort4 hv, mv, lv;
        float x, r;
        x = v.x; hv.x = f2bf(x); r = x - bf2f(hv.x); mv.x = f2bf(r); lv.x = f2bf(r - bf2f(mv.x));
        x = v.y; hv.y = f2bf(x); r = x - bf2f(hv.y); mv.y = f2bf(r); lv.y = f2bf(r - bf2f(mv.y));
        x = v.z; hv.z = f2bf(x); r = x - bf2f(hv.z); mv.z = f2bf(r); lv.z = f2bf(r - bf2f(mv.z));
        x = v.w; hv.w = f2bf(x); r = x - bf2f(hv.w); mv.w = f2bf(r); lv.w = f2bf(r - bf2f(mv.w));
        ((ushort4*)Ih)[i] = hv; ((ushort4*)Im)[i] = mv; ((ushort4*)Il)[i] = lv;
    } else if (bid < 9984) {
        int i = (bid - 9216) * 256 + t;
        float4 v = ((const float4*)lin_w)[i];
        ushort4 hv, mv, lv;
        float x, r;
        x = v.x; hv.x = f2bf(x); r = x - bf2f(hv.x); mv.x = f2bf(r); lv.x = f2bf(r - bf2f(mv.x));
        x = v.y; hv.y = f2bf(x); r = x - bf2f(hv.y); mv.y = f2bf(r); lv.y = f2bf(r - bf2f(mv.y));
        x = v.z; hv.z = f2bf(x); r = x - bf2f(hv.z); mv.z = f2bf(r); lv.z = f2bf(r - bf2f(mv.z));
        x = v.w; hv.w = f2bf(x); r = x - bf2f(hv.w); mv.w = f2bf(r); lv.w = f2bf(r - bf2f(mv.w));
        ((ushort4*)Wh)[i] = hv; ((ushort4*)Wm)[i] = mv; ((ushort4*)Wl)[i] = lv;
    } else if (bid < 10560) {
        int i = (bid - 9984) * 256 + t;
        float4 v = ((const float4*)pos_w)[i];
        ushort4 hv, lv;
        hv.x = f2bf(v.x); lv.x = f2bf(v.x - bf2f(hv.x));
        hv.y = f2bf(v.y); lv.y = f2bf(v.y - bf2f(hv.y));
        hv.z = f2bf(v.z); lv.z = f2bf(v.z - bf2f(hv.z));
        hv.w = f2bf(v.w); lv.w = f2bf(v.w - bf2f(hv.w));
        ((ushort4*)Ph)[i] = hv; ((ushort4*)Pl)[i] = lv;
    } else if (bid < 11136) {
        int l = bid - 10560;
        for (int k = t; k < D_; k += 256) {
            int kk = (k < 384) ? k : k - 384;
            int m = kk >> 1;
            float coord = (k < 384) ? (float)(l / 24) : (float)(l % 24);
            float v = (coord + 1.0f) / 24.000001f * 6.28318530717958647692f;
            float tm = exp2f((float)m * (13.287712379549449f / 192.0f));
            float a = v / tm;
            pos[(size_t)l * D_ + k] = (kk & 1) ? cosf(a) : sinf(a);
        }
    } else {
        int i = (bid - 11136) * 256 + t;
        int b = i / 576, l = i - b * 576;
        rowflag[i] = (mask[b] == l) ? (b + 1) : 0;
    }
}

// ---------------- merged: LN1+ReLU+xsq+X-split  |  esq+E-split ----------------
__global__ __launch_bounds__(256) void k_ln_esq(
    const float* __restrict__ in, const float* __restrict__ w,
    const float* __restrict__ b, float* __restrict__ xq, float* __restrict__ xsq,
    u16* __restrict__ Xh, u16* __restrict__ Xl,
    const float* __restrict__ E, float* __restrict__ esq,
    u16* __restrict__ Eh, u16* __restrict__ El)
{
    __shared__ float red[256];
    int t = threadIdx.x;
    if (blockIdx.x < 9216) {
        int r = blockIdx.x;
        const float* row = in + (size_t)r * D_;
        float v0 = row[t], v1 = row[t + 256], v2 = row[t + 512];
        float mu = block_sum(v0 + v1 + v2, red) * (1.0f / 768.0f);
        float d0 = v0 - mu, d1 = v1 - mu, d2 = v2 - mu;
        float var = block_sum(d0 * d0 + d1 * d1 + d2 * d2, red) * (1.0f / 768.0f);
        float rn = 1.0f / sqrtf(var + 1e-5f);
        float o0 = fmaxf(0.0f, d0 * rn * w[t] + b[t]);
        float o1 = fmaxf(0.0f, d1 * rn * w[t + 256] + b[t + 256]);
        float o2 = fmaxf(0.0f, d2 * rn * w[t + 512] + b[t + 512]);
        float* orow = xq + (size_t)r * D_;
        orow[t] = o0; orow[t + 256] = o1; orow[t + 512] = o2;
        u16 h0 = f2bf(o0), h1 = f2bf(o1), h2 = f2bf(o2);
        Xh[(size_t)r * D_ + t]       = h0;
        Xh[(size_t)r * D_ + t + 256] = h1;
        Xh[(size_t)r * D_ + t + 512] = h2;
        Xl[(size_t)r * D_ + t]       = f2bf(o0 - bf2f(h0));
        Xl[(size_t)r * D_ + t + 256] = f2bf(o1 - bf2f(h1));
        Xl[(size_t)r * D_ + t + 512] = f2bf(o2 - bf2f(h2));
        float q = block_sum(o0 * o0 + o1 * o1 + o2 * o2, red);
        if (t == 0) xsq[r] = q;
    } else {
        int r = blockIdx.x - 9216;
        const float* row = E + (size_t)r * D_;
        float v0 = row[t], v1 = row[t + 256], v2 = row[t + 512];
        u16 h0 = f2bf(v0), h1 = f2bf(v1), h2 = f2bf(v2);
        Eh[(size_t)r * D_ + t]       = h0;
        Eh[(size_t)r * D_ + t + 256] = h1;
        Eh[(size_t)r * D_ + t + 512] = h2;
        El[(size_t)r * D_ + t]       = f2bf(v0 - bf2f(h0));
        El[(size_t)r * D_ + t + 256] = f2bf(v1 - bf2f(h1));
        El[(size_t)r * D_ + t + 512] = f2bf(v2 - bf2f(h2));
        float s = block_sum(v0 * v0 + v1 * v1 + v2 * v2, red);
        if (t == 0) esq[r] = s;
    }
}

// ---------------- threefry2x32 (jax key(42)) ----------------
__device__ inline void threefry2x32(uint32_t x0, uint32_t x1,
                                    uint32_t& o0, uint32_t& o1)
{
    const uint32_t ks0 = 0u, ks1 = 42u;
    const uint32_t ks2 = ks0 ^ ks1 ^ 0x1BD11BDAu;
    uint32_t ks[3] = {ks0, ks1, ks2};
    x0 += ks[0]; x1 += ks[1];
    const int R0[4] = {13, 15, 26, 6};
    const int R1[4] = {17, 29, 16, 24};
    #pragma unroll
    for (int i = 0; i < 5; ++i) {
        const int* R = (i & 1) ? R1 : R0;
        #pragma unroll
        for (int q = 0; q < 4; ++q) {
            x0 += x1;
            x1 = (x1 << R[q]) | (x1 >> (32 - R[q]));
            x1 ^= x0;
        }
        x0 += ks[(i + 1) % 3];
        x1 += ks[(i + 2) % 3] + (uint32_t)(i + 1);
    }
    o0 = x0; o1 = x1;
}

// ---------------- top-10 + softmax + gumbel categorical, 16 rows ----------------
__global__ __launch_bounds__(256) void k_topk_sample(
    const float* __restrict__ d2row, const unsigned long long* __restrict__ amin,
    const int* __restrict__ mask, int* __restrict__ mlabel, int* __restrict__ negsel)
{
    __shared__ float sd2[KCODE];
    __shared__ unsigned long long rbuf[256];
    __shared__ float rfs[256];
    __shared__ int sel[TOPK];
    __shared__ float selv[TOPK];
    __shared__ float sS;
    int b = blockIdx.x, t = threadIdx.x;
    for (int j = t; j < KCODE; j += 256) sd2[j] = d2row[b * KCODE + j];
    __syncthreads();
    for (int p = 0; p < TOPK; ++p) {
        unsigned long long best = ~0ull;
        for (int j = t; j < KCODE; j += 256) {
            bool skip = false;
            for (int q = 0; q < p; ++q) skip = skip || (j == sel[q]);
            if (skip) continue;
            unsigned long long key =
                ((unsigned long long)__float_as_uint(sd2[j]) << 32) | (unsigned)j;
            best = umin64(best, key);
        }
        rbuf[t] = best;
        __syncthreads();
        for (int s = 128; s > 0; s >>= 1) {
            if (t < s) rbuf[t] = umin64(rbuf[t], rbuf[t + s]);
            __syncthreads();
        }
        if (t == 0) {
            sel[p] = (int)(rbuf[0] & 0xFFFFFFFFull);
            selv[p] = __uint_as_float((uint32_t)(rbuf[0] >> 32));
        }
        __syncthreads();
    }
    float d2min = selv[0];
    float part = 0.0f;
    for (int j = t; j < KCODE; j += 256) part += expf(d2min - sd2[j]);
    part = block_sum(part, rfs);
    if (t == 0) sS = part;
    __syncthreads();
    if (t == 0) {
        int rb = b * 576 + mask[b];
        mlabel[b] = (int)(amin[rb] & 0xFFFFFFFFull);
        float S = sS;
        float bestv = 0.0f;
        int samp = 0;
        bool first = true;
        for (int k = 0; k < TOPK; ++k) {
            float pk = expf(d2min - selv[k]) / S;
            float logit = logf(pk);
            unsigned f = (unsigned)(rb * 10 + k);
            uint32_t o0, o1;
            threefry2x32(0u, f, o0, o1);
            uint32_t bits = o0 ^ o1;
            float uu = __uint_as_float(0x3F800000u | (bits >> 9)) - 1.0f;
            uu = uu + 1.1754944e-38f;
            uu = fmaxf(1.1754944e-38f, uu);
            float gum = -logf(-logf(uu));
            float sc = logit + gum;
            if (first || sc > bestv) { bestv = sc; samp = k; first = false; }
        }
        negsel[b] = sel[samp];
    }
}

// ---------------- fused gate + final (verified round 12) ----------------------
__global__ __launch_bounds__(256) void k_gate_final(
    const float* __restrict__ embpt, const float* __restrict__ xq,
    const unsigned long long* __restrict__ amin,
    const int* __restrict__ mlabel, const int* __restrict__ negsel,
    const float* __restrict__ E, const float* __restrict__ pos,
    const float* __restrict__ gw, const float* __restrict__ gb,
    const float* __restrict__ glnw, const float* __restrict__ glnb,
    const float* __restrict__ ow, const float* __restrict__ ob,
    float* __restrict__ outp, float* __restrict__ outn)
{
    __shared__ float red[256];
    __shared__ float ss0, ss1;
    int r = blockIdx.x, t = threadIdx.x;
    int b = r / 576, l = r % 576;
    const float* ep = embpt + (size_t)r * D_;
    const float* xr = xq + (size_t)r * D_;

    float g0 = 0.0f, g1 = 0.0f;
    for (int k = t; k < 1536; k += 256) {
        float v = (k < 768) ? ep[k] : xr[k - 768];
        g0 = fmaf(v, gw[k], g0);
        g1 = fmaf(v, gw[1536 + k], g1);
    }
    g0 = block_sum(g0, red);
    g1 = block_sum(g1, red);
    if (t == 0) {
        g0 += gb[0]; g1 += gb[1];
        float mu = 0.5f * (g0 + g1);
        float h0 = g0 - mu, h1 = g1 - mu;
        float var = 0.5f * (h0 * h0 + h1 * h1);
        float rn = 1.0f / sqrtf(var + 1e-5f);
        float o0 = fmaxf(0.0f, h0 * rn * glnw[0] + glnb[0]);
        float o1 = fmaxf(0.0f, h1 * rn * glnw[1] + glnb[1]);
        float m = fmaxf(o0, o1);
        float e0 = expf(o0 - m), e1 = expf(o1 - m);
        float inv = 1.0f / (e0 + e1);
        ss0 = e0 * inv;
        ss1 = e1 * inv;
    }
    __syncthreads();
    float s0 = ss0, s1 = ss1;

    int ir = (int)(amin[r] & 0xFFFFFFFFull);
    int nidx = (ir == mlabel[b]) ? negsel[b] : ir;
    const float* er = E + (size_t)nidx * D_;
    const float* pr = pos + (size_t)l * D_;
    float vp[3], vn[3];
    #pragma unroll
    for (int q = 0; q < 3; ++q) {
        int k = t + q * 256;
        float xv = xr[k] * s1;
        float pv = pr[k];
        vp[q] = (ep[k] * s0 + xv) + pv;
        vn[q] = (er[k] * s0 + xv) + pv;
    }
    float mup = block_sum(vp[0] + vp[1] + vp[2], red) * (1.0f / 768.0f);
    float a0 = vp[0] - mup, a1 = vp[1] - mup, a2 = vp[2] - mup;
    float varp = block_sum(a0 * a0 + a1 * a1 + a2 * a2, red) * (1.0f / 768.0f);
    float rnp = 1.0f / sqrtf(varp + 1e-5f);
    float mun = block_sum(vn[0] + vn[1] + vn[2], red) * (1.0f / 768.0f);
    float c0 = vn[0] - mun, c1 = vn[1] - mun, c2 = vn[2] - mun;
    float varn = block_sum(c0 * c0 + c1 * c1 + c2 * c2, red) * (1.0f / 768.0f);
    float rnn = 1.0f / sqrtf(varn + 1e-5f);
    float* op = outp + (size_t)r * D_;
    float* on = outn + (size_t)r * D_;
    op[t]       = a0 * rnp * ow[t]       + ob[t];
    op[t + 256] = a1 * rnp * ow[t + 256] + ob[t + 256];
    op[t + 512] = a2 * rnp * ow[t + 512] + ob[t + 512];
    on[t]       = c0 * rnn * ow[t]       + ob[t];
    on[t + 256] = c1 * rnn * ow[t + 256] + ob[t + 256];
    on[t + 512] = c2 * rnn * ow[t + 512] + ob[t + 512];
}

// ---------------- launcher ----------------
extern "C" void kernel_launch(void* const* d_in, const int* in_sizes, int n_in,
                              void* d_out, int out_size, void* d_ws, size_t ws_size,
                              hipStream_t stream)
{
    (void)in_sizes; (void)n_in; (void)out_size; (void)ws_size;
    const float* img    = (const float*)d_in[0];
    const int*   maski  = (const int*)d_in[1];
    const float* lin_w  = (const float*)d_in[2];
    const float* lin_b  = (const float*)d_in[3];
    const float* ln1_w  = (const float*)d_in[4];
    const float* ln1_b  = (const float*)d_in[5];
    const float* embed  = (const float*)d_in[6];
    const float* pos_w  = (const float*)d_in[7];
    const float* pos_b  = (const float*)d_in[8];
    const float* gate_w = (const float*)d_in[9];
    const float* gate_b = (const float*)d_in[10];
    const float* glnw   = (const float*)d_in[11];
    const float* glnb   = (const float*)d_in[12];
    const float* olnw   = (const float*)d_in[13];
    const float* olnb   = (const float*)d_in[14];

    uint8_t* wp = (uint8_t*)d_ws;
    auto alloc = [&](size_t bytes) -> void* {
        void* p = (void*)wp;
        wp += (bytes + 255) & ~(size_t)255;
        return p;
    };
    float* bufA = (float*)alloc((size_t)M_TOT * D_ * 4);   // gemm1 out, later emb_pt
    float* xq   = (float*)alloc((size_t)M_TOT * D_ * 4);
    float* xsq  = (float*)alloc((size_t)M_TOT * 4);
    float* esq  = (float*)alloc((size_t)KCODE * 4);
    unsigned long long* amin = (unsigned long long*)alloc((size_t)M_TOT * 8);
    int*   rowflag = (int*)alloc((size_t)M_TOT * 4);
    float* posb   = (float*)alloc((size_t)576 * D_ * 4);
    float* d2row  = (float*)alloc((size_t)16 * KCODE * 4);
    int*   mlab   = (int*)alloc(16 * 4);
    int*   negsel = (int*)alloc(16 * 4);
    u16* Wh = (u16*)alloc((size_t)D_ * CIN_ * 2);
    u16* Wm = (u16*)alloc((size_t)D_ * CIN_ * 2);
    u16* Wl = (u16*)alloc((size_t)D_ * CIN_ * 2);
    u16* Ph = (u16*)alloc((size_t)D_ * D_ * 2);
    u16* Pl = (u16*)alloc((size_t)D_ * D_ * 2);
    // R region: img 3-way splits (dead after gemm1), then reused for X/E splits
    u16* R  = (u16*)alloc((size_t)3 * M_TOT * CIN_ * 2);
    u16* Ih = R;
    u16* Im = R + (size_t)M_TOT * CIN_;
    u16* Il = R + (size_t)2 * M_TOT * CIN_;
    u16* Xh = R;
    u16* Xl = Xh + (size_t)M_TOT * D_;
    u16* Eh = Xl + (size_t)M_TOT * D_;
    u16* El = Eh + (size_t)KCODE * D_;

    float* outp = (float*)d_out;
    float* outn = outp + (size_t)M_TOT * D_;

    hipMemsetAsync(amin, 0xFF, M_TOT * sizeof(unsigned long long), stream);

    dim3 blk(256);
    // 0) merged prep
    k_prep<<<11172, blk, 0, stream>>>(img, Ih, Im, Il, lin_w, Wh, Wm, Wl,
                                      pos_w, Ph, Pl, posb, maski, rowflag);
    // 1) xq_pre = img @ lin_w^T + lin_b
    k_gemm1_mfma<<<dim3(D_ / 128, M_TOT / 128), blk, 0, stream>>>(
        Ih, Im, Il, Wh, Wm, Wl, lin_b, bufA);
    // 2) merged LN+ReLU+xsq+X-split | esq+E-split
    k_ln_esq<<<17408, blk, 0, stream>>>(bufA, ln1_w, ln1_b, xq, xsq, Xh, Xl,
                                        embed, esq, Eh, El);
    // 3) code-search MFMA GEMM + argmin + masked-row d2 capture
    k_gemm2_mfma<<<dim3(KCODE / 128, M_TOT / 128), blk, 0, stream>>>(
        Xh, Xl, Eh, El, xsq, esq, rowflag, d2row, amin);
    // 4) emb_pt = embed[idx] @ pos_w^T + pos_b
    k_gemm3_mfma<<<dim3(D_ / 128, M_TOT / 128), blk, 0, stream>>>(
        Eh, El, Ph, Pl, amin, pos_b, bufA);
    // 5) top-10 + threefry gumbel categorical
    k_topk_sample<<<16, blk, 0, stream>>>(d2row, amin, maski, mlab, negsel);
    // 6) fused gate + final mix + LN x2
    k_gate_final<<<M_TOT, blk, 0, stream>>>(bufA, xq, amin, mlab, negsel,
                                            embed, posb, gate_w, gate_b,
                                            glnw, glnb, olnw, olnb, outp, outn);
}